// Round 1
// baseline (164.502 us; speedup 1.0000x reference)
//
#include <hip/hip_runtime.h>
#include <math.h>

// SecondOrderChannelAttension on MI355X (gfx950)
// B=32, C=64, H=W=96 -> M=9216, RED=8
//
// Pipeline:
//   K1 gram_k:  per-batch Gram (X X^T) via bf16 MFMA 16x16x32 + channel sums
//   K2 ns_k:    cov = Gram/M - mu mu^T, Newton-Schulz sqrt (12 matmuls, bf16
//               MFMA in LDS, exploiting symmetry of all NS iterates), gate MLP
//   K3 gate_mul: out = x * gate  (memory-bound elementwise)

#define BB 32
#define CC 64
#define MM 9216

typedef __attribute__((ext_vector_type(8))) short bf16x8;
typedef __attribute__((ext_vector_type(4))) float f32x4;

__device__ __forceinline__ short f2bf(float f) {
  unsigned u = __builtin_bit_cast(unsigned, f);
  return (short)(unsigned short)((u + 0x8000u) >> 16);  // round-half-up, fine here
}
__device__ __forceinline__ float bf2f(short h) {
  unsigned u = ((unsigned)(unsigned short)h) << 16;
  return __builtin_bit_cast(float, u);
}

// ---------------- K1: Gram + channel sums ----------------
// grid = BB * NCHUNK blocks, 256 threads (4 waves).
// Wave covers WAVE_M contiguous m-values in NSTEP steps of 32.
// Fragment trick: for Gram, the B-operand fragment (B[k][n] = X[n][k]) has the
// same lane mapping as the A fragment of X rows -> load once, use twice.
#define NCHUNK 8
#define CHUNK_M (MM / NCHUNK)  // 1152
#define WAVE_M (CHUNK_M / 4)   // 288
#define NSTEP (WAVE_M / 32)    // 9

__global__ __launch_bounds__(256) void gram_k(const float* __restrict__ x,
                                              float* __restrict__ covws,
                                              float* __restrict__ sumws) {
  int b = blockIdx.x / NCHUNK;
  int chunk = blockIdx.x % NCHUNK;
  int tid = threadIdx.x;
  int w = tid >> 6, lane = tid & 63;
  int quad = lane >> 4, col = lane & 15;
  const float* xb = x + (size_t)b * CC * MM;
  int mwave = chunk * CHUNK_M + w * WAVE_M;

  f32x4 acc[4][4];
#pragma unroll
  for (int i = 0; i < 4; i++)
#pragma unroll
    for (int j = 0; j < 4; j++) acc[i][j] = (f32x4){0.f, 0.f, 0.f, 0.f};
  float csum[4] = {0.f, 0.f, 0.f, 0.f};

  const float* base[4];
#pragma unroll
  for (int rb = 0; rb < 4; rb++)
    base[rb] = xb + (size_t)(rb * 16 + col) * MM + mwave + quad * 8;

  // software pipeline: prefetch next step's 8 floats/row-block
  float4 cur[4][2];
#pragma unroll
  for (int rb = 0; rb < 4; rb++) {
    cur[rb][0] = *(const float4*)(base[rb]);
    cur[rb][1] = *(const float4*)(base[rb] + 4);
  }
#pragma unroll
  for (int s = 0; s < NSTEP; s++) {
    float4 nxt[4][2];
    if (s + 1 < NSTEP) {
#pragma unroll
      for (int rb = 0; rb < 4; rb++) {
        const float* p = base[rb] + (s + 1) * 32;
        nxt[rb][0] = *(const float4*)(p);
        nxt[rb][1] = *(const float4*)(p + 4);
      }
    }
    bf16x8 frag[4];
#pragma unroll
    for (int rb = 0; rb < 4; rb++) {
      float v0 = cur[rb][0].x, v1 = cur[rb][0].y, v2 = cur[rb][0].z, v3 = cur[rb][0].w;
      float v4 = cur[rb][1].x, v5 = cur[rb][1].y, v6 = cur[rb][1].z, v7 = cur[rb][1].w;
      csum[rb] += ((v0 + v1) + (v2 + v3)) + ((v4 + v5) + (v6 + v7));
      bf16x8 f;
      f[0] = f2bf(v0); f[1] = f2bf(v1); f[2] = f2bf(v2); f[3] = f2bf(v3);
      f[4] = f2bf(v4); f[5] = f2bf(v5); f[6] = f2bf(v6); f[7] = f2bf(v7);
      frag[rb] = f;
    }
#pragma unroll
    for (int i = 0; i < 4; i++)
#pragma unroll
      for (int j = 0; j < 4; j++)
        acc[i][j] = __builtin_amdgcn_mfma_f32_16x16x32_bf16(frag[i], frag[j],
                                                            acc[i][j], 0, 0, 0);
    if (s + 1 < NSTEP) {
#pragma unroll
      for (int rb = 0; rb < 4; rb++) {
        cur[rb][0] = nxt[rb][0];
        cur[rb][1] = nxt[rb][1];
      }
    }
  }

  // block-level reduce of the 4 waves' partial Grams, then global atomics
  __shared__ float red[4][4096];
#pragma unroll
  for (int i = 0; i < 4; i++)
#pragma unroll
    for (int j = 0; j < 4; j++)
#pragma unroll
      for (int r = 0; r < 4; r++)
        red[w][(i * 16 + quad * 4 + r) * 64 + j * 16 + col] = acc[i][j][r];
  __syncthreads();
  float* covb = covws + b * 4096;
#pragma unroll
  for (int e = 0; e < 16; e++) {
    int idx = tid + 256 * e;
    float v = (red[0][idx] + red[1][idx]) + (red[2][idx] + red[3][idx]);
    atomicAdd(covb + idx, v);
  }
  // channel sums: lanes (col, quad) of row-block rb all hold channel rb*16+col
#pragma unroll
  for (int rb = 0; rb < 4; rb++) {
    float c0 = csum[rb];
    c0 += __shfl_xor(c0, 16);
    c0 += __shfl_xor(c0, 32);
    if (quad == 0 && w >= 0) {
      if (lane < 16) atomicAdd(sumws + b * 64 + rb * 16 + lane, c0);
    }
  }
}

// ---------------- K2: Newton-Schulz + gate MLP ----------------
// 64x64 matmul, operands row-major bf16 in LDS. All NS iterates are symmetric
// (polynomials in A), so B[k][n] == Bm[n][k] -> row-major read serves as the
// k-major B fragment.
__device__ __forceinline__ void mm64(short* __restrict__ D, const short* __restrict__ A,
                                     const short* __restrict__ Bm, int tid) {
  int w = tid >> 6, lane = tid & 63, quad = lane >> 4, col = lane & 15;
  f32x4 acc[4];
#pragma unroll
  for (int j = 0; j < 4; j++) acc[j] = (f32x4){0.f, 0.f, 0.f, 0.f};
#pragma unroll
  for (int ks = 0; ks < 2; ks++) {
    int k0 = ks * 32 + quad * 8;
    bf16x8 fa = *(const bf16x8*)(A + (w * 16 + col) * 64 + k0);
#pragma unroll
    for (int j = 0; j < 4; j++) {
      bf16x8 fb = *(const bf16x8*)(Bm + (j * 16 + col) * 64 + k0);
      acc[j] = __builtin_amdgcn_mfma_f32_16x16x32_bf16(fa, fb, acc[j], 0, 0, 0);
    }
  }
#pragma unroll
  for (int j = 0; j < 4; j++)
#pragma unroll
    for (int r = 0; r < 4; r++)
      D[(w * 16 + quad * 4 + r) * 64 + j * 16 + col] = f2bf(acc[j][r]);
}

__device__ __forceinline__ void mmcolsum(const short* __restrict__ A,
                                         const short* __restrict__ Bm,
                                         float* scol, int tid) {
  int w = tid >> 6, lane = tid & 63, quad = lane >> 4, col = lane & 15;
  f32x4 acc[4];
#pragma unroll
  for (int j = 0; j < 4; j++) acc[j] = (f32x4){0.f, 0.f, 0.f, 0.f};
#pragma unroll
  for (int ks = 0; ks < 2; ks++) {
    int k0 = ks * 32 + quad * 8;
    bf16x8 fa = *(const bf16x8*)(A + (w * 16 + col) * 64 + k0);
#pragma unroll
    for (int j = 0; j < 4; j++) {
      bf16x8 fb = *(const bf16x8*)(Bm + (j * 16 + col) * 64 + k0);
      acc[j] = __builtin_amdgcn_mfma_f32_16x16x32_bf16(fa, fb, acc[j], 0, 0, 0);
    }
  }
#pragma unroll
  for (int j = 0; j < 4; j++) {
    float t = (acc[j][0] + acc[j][1]) + (acc[j][2] + acc[j][3]);
    atomicAdd(&scol[j * 16 + col], t);  // sums over all 64 rows across waves/quads
  }
}

__global__ __launch_bounds__(256) void ns_k(const float* __restrict__ covws,
                                            const float* __restrict__ sumws,
                                            const float* __restrict__ w1,
                                            const float* __restrict__ pb1,
                                            const float* __restrict__ w2,
                                            const float* __restrict__ pb2,
                                            float* __restrict__ gatews) {
  __shared__ __align__(16) short nb0[4096], nb1[4096], nb2[4096], nb3[4096], nb4[4096];
  __shared__ float mu[64];
  __shared__ float scol[64];
  __shared__ float hbuf[8];
  __shared__ float normA_sh;
  int b = blockIdx.x;
  int tid = threadIdx.x;
  const float* gram = covws + b * 4096;

  if (tid < 64) mu[tid] = sumws[b * 64 + tid] * (1.0f / MM);
  __syncthreads();
  if (tid < 64) {
    float d = gram[tid * 65] * (1.0f / MM) - mu[tid] * mu[tid];
#pragma unroll
    for (int off = 32; off >= 1; off >>= 1) d += __shfl_down(d, off);
    if (tid == 0) normA_sh = d;
  }
  __syncthreads();
  float rn = 1.0f / normA_sh;
  // A -> nb0, Z = ZY0 = 1.5I - 0.5A -> nb1
#pragma unroll
  for (int e = 0; e < 16; e++) {
    int idx = tid + 256 * e;
    int r = idx >> 6, c = idx & 63;
    float cv = gram[idx] * (1.0f / MM) - mu[r] * mu[c];
    float a = cv * rn;
    nb0[idx] = f2bf(a);
    nb1[idx] = f2bf((r == c ? 1.5f : 0.0f) - 0.5f * a);
  }
  __syncthreads();
  mm64(nb2, nb0, nb1, tid);  // Y = A @ ZY0
  __syncthreads();
  short *pY = nb2, *pZ = nb1, *s0 = nb3, *s1 = nb4, *s2 = nb0;
  for (int it = 0; it < 3; ++it) {
    // T = 1.5I - 0.5 Z -> s0
#pragma unroll
    for (int e = 0; e < 16; e++) {
      int idx = tid + 256 * e;
      int r = idx >> 6, c = idx & 63;
      float z = bf2f(pZ[idx]);
      s0[idx] = f2bf((r == c ? 1.5f : 0.0f) - 0.5f * z);
    }
    __syncthreads();
    mm64(s1, s0, pY, tid);  // W = T @ Y
    __syncthreads();
    mm64(s2, pY, s1, tid);  // Ynew = Y @ W
    mm64(s0, s1, pZ, tid);  // Znew = W @ Z  (overwrites T; W-matmul already fenced)
    __syncthreads();
    short* oY = pY; short* oZ = pZ; short* oW = s1;
    pY = s2; pZ = s0; s0 = oY; s1 = oZ; s2 = oW;
  }
  mm64(s0, pZ, pY, tid);  // P = Z @ Y
  __syncthreads();
#pragma unroll
  for (int e = 0; e < 16; e++) {  // s0 = 3I - P (in place, own elements only)
    int idx = tid + 256 * e;
    int r = idx >> 6, c = idx & 63;
    float p = bf2f(s0[idx]);
    s0[idx] = f2bf((r == c ? 3.0f : 0.0f) - p);
  }
  if (tid < 64) scol[tid] = 0.0f;
  __syncthreads();
  mmcolsum(pY, s0, scol, tid);  // column sums of R = Y @ (3I - P)
  __syncthreads();
  // s[c] = 0.5*sqrt(normA)/64 * scol[c]; h = relu(s@w1^T + b1); gate = sigmoid(h@w2^T + b2)
  if (tid < 8) {
    float sc = 0.5f * sqrtf(normA_sh) * (1.0f / 64.0f);
    float acc = pb1[tid];
    for (int c = 0; c < 64; c++) acc += scol[c] * sc * w1[tid * 64 + c];
    hbuf[tid] = fmaxf(acc, 0.0f);
  }
  __syncthreads();
  if (tid < 64) {
    float acc = pb2[tid];
#pragma unroll
    for (int j = 0; j < 8; j++) acc += hbuf[j] * w2[tid * 8 + j];
    gatews[b * 64 + tid] = 1.0f / (1.0f + __expf(-acc));
  }
}

// ---------------- K3: out = x * gate ----------------
#define N4 (BB * CC * MM / 4)  // 4718592 float4s; 9216/4 = 2304 float4 per (b,c)
__global__ __launch_bounds__(256) void gate_mul(const float* __restrict__ x,
                                                const float* __restrict__ gatews,
                                                float* __restrict__ out) {
  int i = blockIdx.x * 256 + threadIdx.x;
  int bc = i / 2304;
  float g = gatews[bc];
  float4 v = ((const float4*)x)[i];
  v.x *= g; v.y *= g; v.z *= g; v.w *= g;
  ((float4*)out)[i] = v;
}

extern "C" void kernel_launch(void* const* d_in, const int* in_sizes, int n_in,
                              void* d_out, int out_size, void* d_ws, size_t ws_size,
                              hipStream_t stream) {
  const float* x = (const float*)d_in[0];
  const float* w1 = (const float*)d_in[1];
  const float* b1 = (const float*)d_in[2];
  const float* w2 = (const float*)d_in[3];
  const float* b2 = (const float*)d_in[4];
  float* out = (float*)d_out;
  float* ws = (float*)d_ws;
  float* covws = ws;                    // 32*4096 fp32
  float* sumws = ws + BB * 4096;        // 32*64 fp32
  float* gatews = sumws + BB * 64;      // 32*64 fp32

  hipMemsetAsync(ws, 0, (size_t)(BB * 4096 + BB * 64) * sizeof(float), stream);
  gram_k<<<BB * NCHUNK, 256, 0, stream>>>(x, covws, sumws);
  ns_k<<<BB, 256, 0, stream>>>(covws, sumws, w1, b1, w2, b2, gatews);
  gate_mul<<<N4 / 256, 256, 0, stream>>>(x, gatews, out);
}